// Round 2
// baseline (324.240 us; speedup 1.0000x reference)
//
#include <hip/hip_runtime.h>
#include <hip/hip_bf16.h>

typedef __attribute__((ext_vector_type(8))) short short8;
typedef __attribute__((ext_vector_type(4))) float f32x4;

#define MFMA16(a, b, c) __builtin_amdgcn_mfma_f32_16x16x32_bf16((a), (b), (c), 0, 0, 0)

__device__ __forceinline__ unsigned short f2bf(float f) {
    __hip_bfloat16 h = __float2bfloat16(f);
    return __builtin_bit_cast(unsigned short, h);
}

__device__ __forceinline__ short8 cvt8(f32x4 a, f32x4 b) {
    short8 r;
    r[0] = (short)f2bf(a[0]); r[1] = (short)f2bf(a[1]);
    r[2] = (short)f2bf(a[2]); r[3] = (short)f2bf(a[3]);
    r[4] = (short)f2bf(b[0]); r[5] = (short)f2bf(b[1]);
    r[6] = (short)f2bf(b[2]); r[7] = (short)f2bf(b[3]);
    return r;
}

// ---------------------------------------------------------------------------
// Kernel 0: W [2048][128] f32  ->  Wt [128][2048] bf16 (transposed), x3 mats
// ---------------------------------------------------------------------------
__global__ __launch_bounds__(256) void wt_kernel(const float* __restrict__ Wq,
                                                 const float* __restrict__ Wk,
                                                 const float* __restrict__ Wv,
                                                 unsigned short* __restrict__ Wt) {
    const int j = blockIdx.y;
    const float* W = (j == 0) ? Wq : (j == 1) ? Wk : Wv;
    const int idx = blockIdx.x * 256 + threadIdx.x;  // [0, 128*2048)
    const int h = idx >> 11;
    const int c = idx & 2047;
    Wt[(size_t)j * (128 * 2048) + idx] = f2bf(W[c * 128 + h]);
}

// ---------------------------------------------------------------------------
// Kernel 1: qkv = x @ W  (M=16384, N=128 per j, K=2048), bf16 MFMA
//   blockIdx.x = j (0:q 1:k 2:v), blockIdx.y = m-tile (128 rows)
//   128x128 tile, BK=64, 4 waves x (64x64), LDS stride padded to 72 elems
// ---------------------------------------------------------------------------
__global__ __launch_bounds__(256) void qkv_gemm(const float* __restrict__ x,
                                                const unsigned short* __restrict__ Wt,
                                                unsigned short* __restrict__ qkv) {
    constexpr int LDT = 72;  // padded stride (elems); 144 B = 9*16 -> aligned b128
    __shared__ __align__(16) unsigned short As[128 * LDT];
    __shared__ __align__(16) unsigned short Bs[128 * LDT];

    const int tid = threadIdx.x;
    const int l = tid & 63;
    const int w = tid >> 6;
    const int wr = w >> 1, wc = w & 1;
    const int bn = blockIdx.x;
    const int bm = blockIdx.y;
    const int lrow = l & 15, lk = (l >> 4) * 8;

    const float* xA = x + (size_t)bm * 128 * 2048;
    const unsigned short* Wb = Wt + (size_t)bn * (128 * 2048);
    unsigned short* outp = qkv + (size_t)bn * (16384 * 128);

    const f32x4 fzero = {0.f, 0.f, 0.f, 0.f};
    f32x4 acc[4][4];
#pragma unroll
    for (int mt = 0; mt < 4; mt++)
#pragma unroll
        for (int nt = 0; nt < 4; nt++) acc[mt][nt] = fzero;

    for (int kt = 0; kt < 32; kt++) {
        __syncthreads();
        // stage A: 128x64 f32 -> bf16, 1024 chunks of 8 elems, 4 per thread
#pragma unroll
        for (int i = 0; i < 4; i++) {
            const int c = tid + 256 * i;
            const int m = c >> 3;
            const int k0 = (c & 7) * 8;
            const float* src = xA + (size_t)m * 2048 + kt * 64 + k0;
            f32x4 f0 = *(const f32x4*)(src);
            f32x4 f1 = *(const f32x4*)(src + 4);
            *(short8*)&As[m * LDT + k0] = cvt8(f0, f1);
        }
        // stage B: 128x64 bf16 from Wt rows
#pragma unroll
        for (int i = 0; i < 4; i++) {
            const int c = tid + 256 * i;
            const int n = c >> 3;
            const int k0 = (c & 7) * 8;
            short8 bv = *(const short8*)(Wb + (size_t)n * 2048 + kt * 64 + k0);
            *(short8*)&Bs[n * LDT + k0] = bv;
        }
        __syncthreads();
#pragma unroll
        for (int ks = 0; ks < 2; ks++) {
            short8 af[4], bfr[4];
#pragma unroll
            for (int mt = 0; mt < 4; mt++)
                af[mt] = *(const short8*)&As[(wr * 64 + mt * 16 + lrow) * LDT + ks * 32 + lk];
#pragma unroll
            for (int nt = 0; nt < 4; nt++)
                bfr[nt] = *(const short8*)&Bs[(wc * 64 + nt * 16 + lrow) * LDT + ks * 32 + lk];
#pragma unroll
            for (int mt = 0; mt < 4; mt++)
#pragma unroll
                for (int nt = 0; nt < 4; nt++)
                    acc[mt][nt] = MFMA16(af[mt], bfr[nt], acc[mt][nt]);
        }
    }

    const float scale = (bn == 0) ? 0.08838834764831845f : 1.0f;  // 1/sqrt(128) folded into q
#pragma unroll
    for (int mt = 0; mt < 4; mt++)
#pragma unroll
        for (int nt = 0; nt < 4; nt++)
#pragma unroll
            for (int r = 0; r < 4; r++) {
                const int row = bm * 128 + wr * 64 + mt * 16 + (l >> 4) * 4 + r;
                const int col = wc * 64 + nt * 16 + lrow;
                outp[(size_t)row * 128 + col] = f2bf(acc[mt][nt][r] * scale);
            }
}

// ---------------------------------------------------------------------------
// Kernel 2: flash attention, non-causal. blockIdx.x = q-tile (64 rows),
// blockIdx.y = batch. 4 waves x 16 Q rows each, per-wave online softmax.
// KVBLK = 64. K padded LDS; V staged transposed; P via per-wave LDS.
// ---------------------------------------------------------------------------
__global__ __launch_bounds__(256) void attn_kernel(const unsigned short* __restrict__ q,
                                                   const unsigned short* __restrict__ k,
                                                   const unsigned short* __restrict__ v,
                                                   float* __restrict__ out) {
    constexpr int KS = 136;  // 272 B stride (17*16)
    constexpr int VS = 88;   // 176 B stride (11*16)
    constexpr int PS = 88;
    __shared__ __align__(16) unsigned short Ks[64 * KS];
    __shared__ __align__(16) unsigned short Vt[128 * VS];
    __shared__ __align__(16) unsigned short Psh[64 * PS];

    const int tid = threadIdx.x;
    const int l = tid & 63;
    const int w = tid >> 6;
    const int qt = blockIdx.x;
    const int b = blockIdx.y;
    const int lrow = l & 15, g = l >> 4, lk = g * 8;

    // Q fragments held in registers for the whole kernel (scale pre-folded)
    const size_t qbase = ((size_t)b * 2048 + qt * 64 + w * 16 + lrow) * 128;
    short8 qf[4];
#pragma unroll
    for (int ks = 0; ks < 4; ks++) qf[ks] = *(const short8*)(q + qbase + ks * 32 + lk);

    const f32x4 fzero = {0.f, 0.f, 0.f, 0.f};
    float m_r[4], l_r[4];
    f32x4 oacc[8];
#pragma unroll
    for (int r = 0; r < 4; r++) { m_r[r] = -1e30f; l_r[r] = 0.f; }
#pragma unroll
    for (int d = 0; d < 8; d++) oacc[d] = fzero;

    const int skey = tid & 63;        // staging: key = lane (conflict-free Vt writes)
    const int sd = (tid >> 6) * 8;    // staging: d-octet base per wave

    for (int kv = 0; kv < 32; kv++) {
        __syncthreads();
        const size_t kvbase = ((size_t)b * 2048 + kv * 64 + skey) * 128;
#pragma unroll
        for (int jj = 0; jj < 4; jj++) {
            const int d0 = sd + jj * 32;
            short8 kvv = *(const short8*)(k + kvbase + d0);
            *(short8*)&Ks[skey * KS + d0] = kvv;
        }
#pragma unroll
        for (int jj = 0; jj < 4; jj++) {
            const int d0 = sd + jj * 32;
            short8 vv = *(const short8*)(v + kvbase + d0);
#pragma unroll
            for (int e = 0; e < 8; e++)
                Vt[(d0 + e) * VS + skey] = (unsigned short)vv[e];
        }
        __syncthreads();

        // S = Q K^T  (16 q-rows x 64 keys per wave)
        f32x4 s[4];
#pragma unroll
        for (int nt = 0; nt < 4; nt++) s[nt] = fzero;
#pragma unroll
        for (int ks = 0; ks < 4; ks++)
#pragma unroll
            for (int nt = 0; nt < 4; nt++) {
                short8 kf = *(const short8*)&Ks[(nt * 16 + lrow) * KS + ks * 32 + lk];
                s[nt] = MFMA16(qf[ks], kf, s[nt]);
            }

        // online softmax; row = g*4 + r lives in the 16 lanes of group g
        float sf[4];
#pragma unroll
        for (int r = 0; r < 4; r++) {
            float tmax = fmaxf(fmaxf(s[0][r], s[1][r]), fmaxf(s[2][r], s[3][r]));
#pragma unroll
            for (int mk = 8; mk >= 1; mk >>= 1) tmax = fmaxf(tmax, __shfl_xor(tmax, mk));
            const float mnew = fmaxf(m_r[r], tmax);
            sf[r] = __expf(m_r[r] - mnew);
            m_r[r] = mnew;
            float psum = 0.f;
#pragma unroll
            for (int nt = 0; nt < 4; nt++) {
                const float p = __expf(s[nt][r] - mnew);
                s[nt][r] = p;
                psum += p;
            }
#pragma unroll
            for (int mk = 8; mk >= 1; mk >>= 1) psum += __shfl_xor(psum, mk);
            l_r[r] = l_r[r] * sf[r] + psum;
        }
#pragma unroll
        for (int d = 0; d < 8; d++)
#pragma unroll
            for (int r = 0; r < 4; r++) oacc[d][r] *= sf[r];

        // P -> LDS (per-wave private rows), then PV
#pragma unroll
        for (int nt = 0; nt < 4; nt++)
#pragma unroll
            for (int r = 0; r < 4; r++)
                Psh[(w * 16 + g * 4 + r) * PS + nt * 16 + lrow] = f2bf(s[nt][r]);
        __syncthreads();

#pragma unroll
        for (int ks2 = 0; ks2 < 2; ks2++) {
            short8 pa = *(const short8*)&Psh[(w * 16 + lrow) * PS + ks2 * 32 + lk];
#pragma unroll
            for (int dt = 0; dt < 8; dt++) {
                short8 vbf = *(const short8*)&Vt[(dt * 16 + lrow) * VS + ks2 * 32 + lk];
                oacc[dt] = MFMA16(pa, vbf, oacc[dt]);
            }
        }
    }

    // epilogue: divide by row sums, write f32
#pragma unroll
    for (int r = 0; r < 4; r++) {
        const float inv = 1.0f / l_r[r];
        const size_t rowbase = ((size_t)b * 2048 + qt * 64 + w * 16 + g * 4 + r) * 128;
#pragma unroll
        for (int dt = 0; dt < 8; dt++)
            out[rowbase + dt * 16 + lrow] = oacc[dt][r] * inv;
    }
}

// ---------------------------------------------------------------------------
extern "C" void kernel_launch(void* const* d_in, const int* in_sizes, int n_in,
                              void* d_out, int out_size, void* d_ws, size_t ws_size,
                              hipStream_t stream) {
    const float* x  = (const float*)d_in[0];
    const float* Wq = (const float*)d_in[1];
    const float* Wk = (const float*)d_in[2];
    const float* Wv = (const float*)d_in[3];
    float* out = (float*)d_out;

    unsigned short* ws = (unsigned short*)d_ws;
    unsigned short* qb = ws;                                   // 16384*128 bf16
    unsigned short* kb = qb + (size_t)16384 * 128;
    unsigned short* vb = kb + (size_t)16384 * 128;
    unsigned short* Wt = vb + (size_t)16384 * 128;             // 3*128*2048 bf16

    hipLaunchKernelGGL(wt_kernel, dim3(1024, 3), dim3(256), 0, stream, Wq, Wk, Wv, Wt);
    hipLaunchKernelGGL(qkv_gemm, dim3(3, 128), dim3(256), 0, stream, x, Wt, qb);
    hipLaunchKernelGGL(attn_kernel, dim3(32, 8), dim3(256), 0, stream, qb, kb, vb, out);
}

// Round 4
// 295.873 us; speedup vs baseline: 1.0959x; 1.0959x over previous
//
#include <hip/hip_runtime.h>
#include <hip/hip_bf16.h>

typedef __attribute__((ext_vector_type(8))) short short8;
typedef __attribute__((ext_vector_type(4))) float f32x4;

#define MFMA16(a, b, c) __builtin_amdgcn_mfma_f32_16x16x32_bf16((a), (b), (c), 0, 0, 0)

__device__ __forceinline__ unsigned short f2bf(float f) {
    __hip_bfloat16 h = __float2bfloat16(f);
    return __builtin_bit_cast(unsigned short, h);
}

__device__ __forceinline__ short8 cvt8(f32x4 a, f32x4 b) {
    short8 r;
    r[0] = (short)f2bf(a[0]); r[1] = (short)f2bf(a[1]);
    r[2] = (short)f2bf(a[2]); r[3] = (short)f2bf(a[3]);
    r[4] = (short)f2bf(b[0]); r[5] = (short)f2bf(b[1]);
    r[6] = (short)f2bf(b[2]); r[7] = (short)f2bf(b[3]);
    return r;
}

// ---------------------------------------------------------------------------
// Kernel 0: W [2048][128] f32 -> Wt [128][2048] bf16, via 64x64 LDS transpose.
// grid (32, 2, 3), block 256. Coalesced reads AND writes.
// ---------------------------------------------------------------------------
__global__ __launch_bounds__(256) void wt_kernel(const float* __restrict__ Wq,
                                                 const float* __restrict__ Wk,
                                                 const float* __restrict__ Wv,
                                                 unsigned short* __restrict__ Wt) {
    __shared__ float T[64][65];
    const int j = blockIdx.z;
    const float* W = (j == 0) ? Wq : (j == 1) ? Wk : Wv;
    const int c0 = blockIdx.x * 64;
    const int h0 = blockIdx.y * 64;
    const int tid = threadIdx.x;

#pragma unroll
    for (int i = 0; i < 4; i++) {
        const int cc = tid + 256 * i;          // 1024 f32x4 chunks
        const int r = cc >> 4;                 // 0..63 (c-row)
        const int q4 = (cc & 15) * 4;          // 0..60 (h-col)
        f32x4 vv = *(const f32x4*)(W + (size_t)(c0 + r) * 128 + h0 + q4);
        T[r][q4 + 0] = vv[0]; T[r][q4 + 1] = vv[1];
        T[r][q4 + 2] = vv[2]; T[r][q4 + 3] = vv[3];
    }
    __syncthreads();
#pragma unroll
    for (int i = 0; i < 2; i++) {
        const int oc = tid + 256 * i;          // 512 short8 chunks
        const int hr = oc >> 3;                // 0..63 (h-row)
        const int c8 = (oc & 7) * 8;           // 0..56 (c-col)
        short8 r;
#pragma unroll
        for (int e = 0; e < 8; e++) r[e] = (short)f2bf(T[c8 + e][hr]);
        *(short8*)(Wt + (size_t)j * (128 * 2048) + (size_t)(h0 + hr) * 2048 + c0 + c8) = r;
    }
}

// ---------------------------------------------------------------------------
// Kernel 1: qkv = x @ W  (M=16384, N=128 per j, K=2048), bf16 MFMA
// ---------------------------------------------------------------------------
__global__ __launch_bounds__(256) void qkv_gemm(const float* __restrict__ x,
                                                const unsigned short* __restrict__ Wt,
                                                unsigned short* __restrict__ qkv) {
    constexpr int LDT = 72;
    __shared__ __align__(16) unsigned short As[128 * LDT];
    __shared__ __align__(16) unsigned short Bs[128 * LDT];

    const int tid = threadIdx.x;
    const int l = tid & 63;
    const int w = tid >> 6;
    const int wr = w >> 1, wc = w & 1;
    const int bn = blockIdx.x;
    const int bm = blockIdx.y;
    const int lrow = l & 15, lk = (l >> 4) * 8;

    const float* xA = x + (size_t)bm * 128 * 2048;
    const unsigned short* Wb = Wt + (size_t)bn * (128 * 2048);
    unsigned short* outp = qkv + (size_t)bn * (16384 * 128);

    const f32x4 fzero = {0.f, 0.f, 0.f, 0.f};
    f32x4 acc[4][4];
#pragma unroll
    for (int mt = 0; mt < 4; mt++)
#pragma unroll
        for (int nt = 0; nt < 4; nt++) acc[mt][nt] = fzero;

    for (int kt = 0; kt < 32; kt++) {
        __syncthreads();
#pragma unroll
        for (int i = 0; i < 4; i++) {
            const int c = tid + 256 * i;
            const int m = c >> 3;
            const int k0 = (c & 7) * 8;
            const float* src = xA + (size_t)m * 2048 + kt * 64 + k0;
            f32x4 f0 = *(const f32x4*)(src);
            f32x4 f1 = *(const f32x4*)(src + 4);
            *(short8*)&As[m * LDT + k0] = cvt8(f0, f1);
        }
#pragma unroll
        for (int i = 0; i < 4; i++) {
            const int c = tid + 256 * i;
            const int n = c >> 3;
            const int k0 = (c & 7) * 8;
            short8 bv = *(const short8*)(Wb + (size_t)n * 2048 + kt * 64 + k0);
            *(short8*)&Bs[n * LDT + k0] = bv;
        }
        __syncthreads();
#pragma unroll
        for (int ks = 0; ks < 2; ks++) {
            short8 af[4], bfr[4];
#pragma unroll
            for (int mt = 0; mt < 4; mt++)
                af[mt] = *(const short8*)&As[(wr * 64 + mt * 16 + lrow) * LDT + ks * 32 + lk];
#pragma unroll
            for (int nt = 0; nt < 4; nt++)
                bfr[nt] = *(const short8*)&Bs[(wc * 64 + nt * 16 + lrow) * LDT + ks * 32 + lk];
#pragma unroll
            for (int mt = 0; mt < 4; mt++)
#pragma unroll
                for (int nt = 0; nt < 4; nt++)
                    acc[mt][nt] = MFMA16(af[mt], bfr[nt], acc[mt][nt]);
        }
    }

    const float scale = (bn == 0) ? 0.08838834764831845f : 1.0f;
#pragma unroll
    for (int mt = 0; mt < 4; mt++)
#pragma unroll
        for (int nt = 0; nt < 4; nt++)
#pragma unroll
            for (int r = 0; r < 4; r++) {
                const int row = bm * 128 + wr * 64 + mt * 16 + (l >> 4) * 4 + r;
                const int col = wc * 64 + nt * 16 + lrow;
                outp[(size_t)row * 128 + col] = f2bf(acc[mt][nt][r] * scale);
            }
}

// ---------------------------------------------------------------------------
// Kernel 2a: split-KV flash attention partials.
// grid (32 qtiles, 8 batches, 3 splits); block 256 (4 waves x 16 q rows).
// Each split handles ~11 of the 32 KV tiles; writes unnormalized O + (m,l).
// ---------------------------------------------------------------------------
template <bool SPLIT>
__global__ __launch_bounds__(256) void attn_kernel_t(const unsigned short* __restrict__ q,
                                                     const unsigned short* __restrict__ k,
                                                     const unsigned short* __restrict__ v,
                                                     float* __restrict__ Oout,
                                                     float* __restrict__ Ml) {
    constexpr int KS = 136;
    constexpr int VS = 88;
    constexpr int PS = 88;
    __shared__ __align__(16) unsigned short Ks[64 * KS];
    __shared__ __align__(16) unsigned short Vt[128 * VS];
    __shared__ __align__(16) unsigned short Psh[64 * PS];

    const int tid = threadIdx.x;
    const int l = tid & 63;
    const int w = tid >> 6;
    const int qt = blockIdx.x;
    const int b = blockIdx.y;
    const int s = SPLIT ? blockIdx.z : 0;
    const int kv_beg = SPLIT ? s * 11 : 0;
    const int kv_end = SPLIT ? ((s == 2) ? 32 : kv_beg + 11) : 32;
    const int lrow = l & 15, g = l >> 4, lk = g * 8;

    const size_t qbase = ((size_t)b * 2048 + qt * 64 + w * 16 + lrow) * 128;
    short8 qf[4];
#pragma unroll
    for (int ks = 0; ks < 4; ks++) qf[ks] = *(const short8*)(q + qbase + ks * 32 + lk);

    const f32x4 fzero = {0.f, 0.f, 0.f, 0.f};
    float m_r[4], l_r[4];
    f32x4 oacc[8];
#pragma unroll
    for (int r = 0; r < 4; r++) { m_r[r] = -1e30f; l_r[r] = 0.f; }
#pragma unroll
    for (int d = 0; d < 8; d++) oacc[d] = fzero;

    const int skey = tid & 63;
    const int sd = (tid >> 6) * 8;

    for (int kv = kv_beg; kv < kv_end; kv++) {
        __syncthreads();
        const size_t kvbase = ((size_t)b * 2048 + kv * 64 + skey) * 128;
#pragma unroll
        for (int jj = 0; jj < 4; jj++) {
            const int d0 = sd + jj * 32;
            short8 kvv = *(const short8*)(k + kvbase + d0);
            *(short8*)&Ks[skey * KS + d0] = kvv;
        }
#pragma unroll
        for (int jj = 0; jj < 4; jj++) {
            const int d0 = sd + jj * 32;
            short8 vv = *(const short8*)(v + kvbase + d0);
#pragma unroll
            for (int e = 0; e < 8; e++)
                Vt[(d0 + e) * VS + skey] = (unsigned short)vv[e];
        }
        __syncthreads();

        f32x4 sv[4];
#pragma unroll
        for (int nt = 0; nt < 4; nt++) sv[nt] = fzero;
#pragma unroll
        for (int ks = 0; ks < 4; ks++)
#pragma unroll
            for (int nt = 0; nt < 4; nt++) {
                short8 kf = *(const short8*)&Ks[(nt * 16 + lrow) * KS + ks * 32 + lk];
                sv[nt] = MFMA16(qf[ks], kf, sv[nt]);
            }

        float sf[4];
#pragma unroll
        for (int r = 0; r < 4; r++) {
            float tmax = fmaxf(fmaxf(sv[0][r], sv[1][r]), fmaxf(sv[2][r], sv[3][r]));
#pragma unroll
            for (int mk = 8; mk >= 1; mk >>= 1) tmax = fmaxf(tmax, __shfl_xor(tmax, mk));
            const float mnew = fmaxf(m_r[r], tmax);
            sf[r] = __expf(m_r[r] - mnew);
            m_r[r] = mnew;
            float psum = 0.f;
#pragma unroll
            for (int nt = 0; nt < 4; nt++) {
                const float p = __expf(sv[nt][r] - mnew);
                sv[nt][r] = p;
                psum += p;
            }
#pragma unroll
            for (int mk = 8; mk >= 1; mk >>= 1) psum += __shfl_xor(psum, mk);
            l_r[r] = l_r[r] * sf[r] + psum;
        }
#pragma unroll
        for (int d = 0; d < 8; d++)
#pragma unroll
            for (int r = 0; r < 4; r++) oacc[d][r] *= sf[r];

#pragma unroll
        for (int nt = 0; nt < 4; nt++)
#pragma unroll
            for (int r = 0; r < 4; r++)
                Psh[(w * 16 + g * 4 + r) * PS + nt * 16 + lrow] = f2bf(sv[nt][r]);
        __syncthreads();

#pragma unroll
        for (int ks2 = 0; ks2 < 2; ks2++) {
            short8 pa = *(const short8*)&Psh[(w * 16 + lrow) * PS + ks2 * 32 + lk];
#pragma unroll
            for (int dt = 0; dt < 8; dt++) {
                short8 vbf = *(const short8*)&Vt[(dt * 16 + lrow) * VS + ks2 * 32 + lk];
                oacc[dt] = MFMA16(pa, vbf, oacc[dt]);
            }
        }
    }

#pragma unroll
    for (int r = 0; r < 4; r++) {
        const int rowi = b * 2048 + qt * 64 + w * 16 + g * 4 + r;
        if (SPLIT) {
            const size_t obase = ((size_t)s * 16384 + rowi) * 128;
#pragma unroll
            for (int dt = 0; dt < 8; dt++)
                Oout[obase + dt * 16 + lrow] = oacc[dt][r];
            if (lrow == 0) {
                const size_t mb = ((size_t)s * 16384 + rowi) * 2;
                Ml[mb] = m_r[r];
                Ml[mb + 1] = l_r[r];
            }
        } else {
            const float inv = 1.0f / l_r[r];
#pragma unroll
            for (int dt = 0; dt < 8; dt++)
                Oout[(size_t)rowi * 128 + dt * 16 + lrow] = oacc[dt][r] * inv;
        }
    }
}

// ---------------------------------------------------------------------------
// Kernel 2b: merge 3 split partials. block 256 = 2 rows x 128 cols.
// ---------------------------------------------------------------------------
__global__ __launch_bounds__(256) void attn_merge(const float* __restrict__ Oacc,
                                                  const float* __restrict__ Ml,
                                                  float* __restrict__ out) {
    const int row = blockIdx.x * 2 + (threadIdx.x >> 7);
    const int c = threadIdx.x & 127;
    const float m0 = Ml[(size_t)(0 * 16384 + row) * 2], l0 = Ml[(size_t)(0 * 16384 + row) * 2 + 1];
    const float m1 = Ml[(size_t)(1 * 16384 + row) * 2], l1 = Ml[(size_t)(1 * 16384 + row) * 2 + 1];
    const float m2 = Ml[(size_t)(2 * 16384 + row) * 2], l2 = Ml[(size_t)(2 * 16384 + row) * 2 + 1];
    const float M = fmaxf(m0, fmaxf(m1, m2));
    const float w0 = __expf(m0 - M), w1 = __expf(m1 - M), w2 = __expf(m2 - M);
    const float D = w0 * l0 + w1 * l1 + w2 * l2;
    const float o = w0 * Oacc[(size_t)(0 * 16384 + row) * 128 + c] +
                    w1 * Oacc[(size_t)(1 * 16384 + row) * 128 + c] +
                    w2 * Oacc[(size_t)(2 * 16384 + row) * 128 + c];
    out[(size_t)row * 128 + c] = o / D;
}

// ---------------------------------------------------------------------------
extern "C" void kernel_launch(void* const* d_in, const int* in_sizes, int n_in,
                              void* d_out, int out_size, void* d_ws, size_t ws_size,
                              hipStream_t stream) {
    const float* x  = (const float*)d_in[0];
    const float* Wq = (const float*)d_in[1];
    const float* Wk = (const float*)d_in[2];
    const float* Wv = (const float*)d_in[3];
    float* out = (float*)d_out;

    unsigned short* ws = (unsigned short*)d_ws;
    unsigned short* qb = ws;                                   // 16384*128 bf16
    unsigned short* kb = qb + (size_t)16384 * 128;
    unsigned short* vb = kb + (size_t)16384 * 128;
    unsigned short* Wt = vb + (size_t)16384 * 128;             // 3*128*2048 bf16
    float* Oacc = (float*)(Wt + (size_t)3 * 128 * 2048);       // 3*16384*128 f32
    float* Ml = Oacc + (size_t)3 * 16384 * 128;                // 3*16384*2 f32
    const size_t ws_need = (size_t)((char*)(Ml + (size_t)3 * 16384 * 2) - (char*)d_ws);

    hipLaunchKernelGGL(wt_kernel, dim3(32, 2, 3), dim3(256), 0, stream, Wq, Wk, Wv, Wt);
    hipLaunchKernelGGL(qkv_gemm, dim3(3, 128), dim3(256), 0, stream, x, Wt, qb);
    if (ws_size >= ws_need) {
        hipLaunchKernelGGL((attn_kernel_t<true>), dim3(32, 8, 3), dim3(256), 0, stream,
                           qb, kb, vb, Oacc, Ml);
        hipLaunchKernelGGL(attn_merge, dim3(8192), dim3(256), 0, stream, Oacc, Ml, out);
    } else {
        hipLaunchKernelGGL((attn_kernel_t<false>), dim3(32, 8), dim3(256), 0, stream,
                           qb, kb, vb, out, (float*)nullptr);
    }
}

// Round 5
// 292.997 us; speedup vs baseline: 1.1066x; 1.0098x over previous
//
#include <hip/hip_runtime.h>
#include <hip/hip_bf16.h>

typedef __attribute__((ext_vector_type(8))) short short8;
typedef __attribute__((ext_vector_type(4))) float f32x4;

#define MFMA16(a, b, c) __builtin_amdgcn_mfma_f32_16x16x32_bf16((a), (b), (c), 0, 0, 0)

#define GLOAD_LDS16(gp, lp)                                                            \
    __builtin_amdgcn_global_load_lds(                                                  \
        (const __attribute__((address_space(1))) unsigned int*)(gp),                   \
        (__attribute__((address_space(3))) unsigned int*)(lp), 16, 0, 0)

__device__ __forceinline__ unsigned short f2bf(float f) {
    __hip_bfloat16 h = __float2bfloat16(f);
    return __builtin_bit_cast(unsigned short, h);
}

__device__ __forceinline__ short8 cvt8(f32x4 a, f32x4 b) {
    short8 r;
    r[0] = (short)f2bf(a[0]); r[1] = (short)f2bf(a[1]);
    r[2] = (short)f2bf(a[2]); r[3] = (short)f2bf(a[3]);
    r[4] = (short)f2bf(b[0]); r[5] = (short)f2bf(b[1]);
    r[6] = (short)f2bf(b[2]); r[7] = (short)f2bf(b[3]);
    return r;
}

// ---------------------------------------------------------------------------
// Kernel 0: W [2048][128] f32 -> Wt [128][2048] bf16, via 64x64 LDS transpose.
// ---------------------------------------------------------------------------
__global__ __launch_bounds__(256) void wt_kernel(const float* __restrict__ Wq,
                                                 const float* __restrict__ Wk,
                                                 const float* __restrict__ Wv,
                                                 unsigned short* __restrict__ Wt) {
    __shared__ float T[64][65];
    const int j = blockIdx.z;
    const float* W = (j == 0) ? Wq : (j == 1) ? Wk : Wv;
    const int c0 = blockIdx.x * 64;
    const int h0 = blockIdx.y * 64;
    const int tid = threadIdx.x;

#pragma unroll
    for (int i = 0; i < 4; i++) {
        const int cc = tid + 256 * i;
        const int r = cc >> 4;
        const int q4 = (cc & 15) * 4;
        f32x4 vv = *(const f32x4*)(W + (size_t)(c0 + r) * 128 + h0 + q4);
        T[r][q4 + 0] = vv[0]; T[r][q4 + 1] = vv[1];
        T[r][q4 + 2] = vv[2]; T[r][q4 + 3] = vv[3];
    }
    __syncthreads();
#pragma unroll
    for (int i = 0; i < 2; i++) {
        const int oc = tid + 256 * i;
        const int hr = oc >> 3;
        const int c8 = (oc & 7) * 8;
        short8 r;
#pragma unroll
        for (int e = 0; e < 8; e++) r[e] = (short)f2bf(T[c8 + e][hr]);
        *(short8*)(Wt + (size_t)j * (128 * 2048) + (size_t)(h0 + hr) * 2048 + c0 + c8) = r;
    }
}

// ---------------------------------------------------------------------------
// Kernel 1 v2: qkv = x @ W. BM=64, BN=128, BK=64. Grid 768 linear blocks,
// XCD-remapped so the 3 bn-blocks of one bm share an XCD (x L2 reuse).
// Double-buffered: B via global_load_lds (XOR-swizzled src/reads), A via
// reg-staged f32->bf16 cvt. One barrier per K-tile.
// ---------------------------------------------------------------------------
__global__ __launch_bounds__(256, 3) void qkv_gemm(const float* __restrict__ x,
                                                   const unsigned short* __restrict__ Wt,
                                                   unsigned short* __restrict__ qkv) {
    constexpr int LDA = 72;  // padded A stride (elems)
    __shared__ __align__(16) unsigned short As[2][64 * LDA];
    __shared__ __align__(16) unsigned short Bs[2][128 * 64];  // swizzled layout

    const int tid = threadIdx.x;
    const int l = tid & 63;
    const int w = tid >> 6;
    const int wr = w >> 1, wc = w & 1;
    const int lrow = l & 15, g = l >> 4, lk = g * 8;

    // XCD remap: 768 = 8 * 96; hw position p -> wg; same-bm triple on one XCD
    const int p = blockIdx.x;
    const int wg = (p & 7) * 96 + (p >> 3);
    const int bn = wg % 3;
    const int bm = wg / 3;

    const float* xA = x + (size_t)bm * 64 * 2048;
    const unsigned short* Wb = Wt + (size_t)bn * (128 * 2048);
    unsigned short* outp = qkv + (size_t)bn * (16384 * 128);

    // A staging map: thread -> (rowA, quad) ; 16 f32 -> 16 bf16 per thread
    const int rowA = tid >> 2;
    const int quad = tid & 3;
    const float* srcA0 = xA + (size_t)rowA * 2048 + quad * 16;

    // B staging map (per gll instr i): row = w*32 + i*8 + (l>>3), 16B slot (l&7)
    const int brow_base = (w << 5) + (l >> 3);
    const int bsw = ((l >> 3) & 7) << 4;                 // XOR swizzle bits (bytes)
    const int bslot = (l & 7) << 4;                      // linear 16B slot (bytes)
    const int bsrc_off = ((bslot ^ bsw) >> 1);           // element offset within 64

    const f32x4 fzero = {0.f, 0.f, 0.f, 0.f};
    f32x4 acc[2][4];
#pragma unroll
    for (int mt = 0; mt < 2; mt++)
#pragma unroll
        for (int nt = 0; nt < 4; nt++) acc[mt][nt] = fzero;

    // ---- prologue: stage kt=0 into buf 0
#pragma unroll
    for (int i = 0; i < 4; i++) {
        const int row = brow_base + (i << 3);
        GLOAD_LDS16(Wb + (size_t)row * 2048 + bsrc_off,
                    &Bs[0][(w << 11) + (i << 9)]);
    }
    {
        f32x4 a0 = *(const f32x4*)(srcA0);
        f32x4 a1 = *(const f32x4*)(srcA0 + 4);
        f32x4 a2 = *(const f32x4*)(srcA0 + 8);
        f32x4 a3 = *(const f32x4*)(srcA0 + 12);
        *(short8*)&As[0][rowA * LDA + quad * 16] = cvt8(a0, a1);
        *(short8*)&As[0][rowA * LDA + quad * 16 + 8] = cvt8(a2, a3);
    }
    __syncthreads();

    int cur = 0;
    for (int kt = 0; kt < 32; kt++) {
        f32x4 a0, a1, a2, a3;
        if (kt < 31) {
            // issue next B tile (async -> LDS, buf cur^1)
#pragma unroll
            for (int i = 0; i < 4; i++) {
                const int row = brow_base + (i << 3);
                GLOAD_LDS16(Wb + (size_t)row * 2048 + (kt + 1) * 64 + bsrc_off,
                            &Bs[cur ^ 1][(w << 11) + (i << 9)]);
            }
            // issue next A loads (regs)
            const float* sA = srcA0 + (kt + 1) * 64;
            a0 = *(const f32x4*)(sA);
            a1 = *(const f32x4*)(sA + 4);
            a2 = *(const f32x4*)(sA + 8);
            a3 = *(const f32x4*)(sA + 12);
        }

        // compute current tile
#pragma unroll
        for (int ks = 0; ks < 2; ks++) {
            short8 af[2], bfr[4];
#pragma unroll
            for (int mt = 0; mt < 2; mt++)
                af[mt] = *(const short8*)&As[cur][(wr * 32 + mt * 16 + lrow) * LDA + ks * 32 + lk];
#pragma unroll
            for (int nt = 0; nt < 4; nt++) {
                const int n = wc * 64 + nt * 16 + lrow;
                const int kbyte = (ks * 64 + g * 16) ^ ((n & 7) << 4);
                bfr[nt] = *(const short8*)&Bs[cur][n * 64 + (kbyte >> 1)];
            }
#pragma unroll
            for (int mt = 0; mt < 2; mt++)
#pragma unroll
                for (int nt = 0; nt < 4; nt++)
                    acc[mt][nt] = MFMA16(af[mt], bfr[nt], acc[mt][nt]);
        }

        if (kt < 31) {
            // cvt + write next A tile (compiler inserts vmcnt for a0..a3)
            *(short8*)&As[cur ^ 1][rowA * LDA + quad * 16] = cvt8(a0, a1);
            *(short8*)&As[cur ^ 1][rowA * LDA + quad * 16 + 8] = cvt8(a2, a3);
        }
        __syncthreads();
        cur ^= 1;
    }

    const float scale = (bn == 0) ? 0.08838834764831845f : 1.0f;
#pragma unroll
    for (int mt = 0; mt < 2; mt++)
#pragma unroll
        for (int nt = 0; nt < 4; nt++)
#pragma unroll
            for (int r = 0; r < 4; r++) {
                const int row = bm * 64 + wr * 32 + mt * 16 + g * 4 + r;
                const int col = wc * 64 + nt * 16 + lrow;
                outp[(size_t)row * 128 + col] = f2bf(acc[mt][nt][r] * scale);
            }
}

// ---------------------------------------------------------------------------
// Kernel 2a: split-KV flash attention partials (unchanged from round 4).
// ---------------------------------------------------------------------------
template <bool SPLIT>
__global__ __launch_bounds__(256) void attn_kernel_t(const unsigned short* __restrict__ q,
                                                     const unsigned short* __restrict__ k,
                                                     const unsigned short* __restrict__ v,
                                                     float* __restrict__ Oout,
                                                     float* __restrict__ Ml) {
    constexpr int KS = 136;
    constexpr int VS = 88;
    constexpr int PS = 88;
    __shared__ __align__(16) unsigned short Ks[64 * KS];
    __shared__ __align__(16) unsigned short Vt[128 * VS];
    __shared__ __align__(16) unsigned short Psh[64 * PS];

    const int tid = threadIdx.x;
    const int l = tid & 63;
    const int w = tid >> 6;
    const int qt = blockIdx.x;
    const int b = blockIdx.y;
    const int s = SPLIT ? blockIdx.z : 0;
    const int kv_beg = SPLIT ? s * 11 : 0;
    const int kv_end = SPLIT ? ((s == 2) ? 32 : kv_beg + 11) : 32;
    const int lrow = l & 15, g = l >> 4, lk = g * 8;

    const size_t qbase = ((size_t)b * 2048 + qt * 64 + w * 16 + lrow) * 128;
    short8 qf[4];
#pragma unroll
    for (int ks = 0; ks < 4; ks++) qf[ks] = *(const short8*)(q + qbase + ks * 32 + lk);

    const f32x4 fzero = {0.f, 0.f, 0.f, 0.f};
    float m_r[4], l_r[4];
    f32x4 oacc[8];
#pragma unroll
    for (int r = 0; r < 4; r++) { m_r[r] = -1e30f; l_r[r] = 0.f; }
#pragma unroll
    for (int d = 0; d < 8; d++) oacc[d] = fzero;

    const int skey = tid & 63;
    const int sd = (tid >> 6) * 8;

    for (int kv = kv_beg; kv < kv_end; kv++) {
        __syncthreads();
        const size_t kvbase = ((size_t)b * 2048 + kv * 64 + skey) * 128;
#pragma unroll
        for (int jj = 0; jj < 4; jj++) {
            const int d0 = sd + jj * 32;
            short8 kvv = *(const short8*)(k + kvbase + d0);
            *(short8*)&Ks[skey * KS + d0] = kvv;
        }
#pragma unroll
        for (int jj = 0; jj < 4; jj++) {
            const int d0 = sd + jj * 32;
            short8 vv = *(const short8*)(v + kvbase + d0);
#pragma unroll
            for (int e = 0; e < 8; e++)
                Vt[(d0 + e) * VS + skey] = (unsigned short)vv[e];
        }
        __syncthreads();

        f32x4 sv[4];
#pragma unroll
        for (int nt = 0; nt < 4; nt++) sv[nt] = fzero;
#pragma unroll
        for (int ks = 0; ks < 4; ks++)
#pragma unroll
            for (int nt = 0; nt < 4; nt++) {
                short8 kf = *(const short8*)&Ks[(nt * 16 + lrow) * KS + ks * 32 + lk];
                sv[nt] = MFMA16(qf[ks], kf, sv[nt]);
            }

        float sf[4];
#pragma unroll
        for (int r = 0; r < 4; r++) {
            float tmax = fmaxf(fmaxf(sv[0][r], sv[1][r]), fmaxf(sv[2][r], sv[3][r]));
#pragma unroll
            for (int mk = 8; mk >= 1; mk >>= 1) tmax = fmaxf(tmax, __shfl_xor(tmax, mk));
            const float mnew = fmaxf(m_r[r], tmax);
            sf[r] = __expf(m_r[r] - mnew);
            m_r[r] = mnew;
            float psum = 0.f;
#pragma unroll
            for (int nt = 0; nt < 4; nt++) {
                const float pp = __expf(sv[nt][r] - mnew);
                sv[nt][r] = pp;
                psum += pp;
            }
#pragma unroll
            for (int mk = 8; mk >= 1; mk >>= 1) psum += __shfl_xor(psum, mk);
            l_r[r] = l_r[r] * sf[r] + psum;
        }
#pragma unroll
        for (int d = 0; d < 8; d++)
#pragma unroll
            for (int r = 0; r < 4; r++) oacc[d][r] *= sf[r];

#pragma unroll
        for (int nt = 0; nt < 4; nt++)
#pragma unroll
            for (int r = 0; r < 4; r++)
                Psh[(w * 16 + g * 4 + r) * PS + nt * 16 + lrow] = f2bf(sv[nt][r]);
        __syncthreads();

#pragma unroll
        for (int ks2 = 0; ks2 < 2; ks2++) {
            short8 pa = *(const short8*)&Psh[(w * 16 + lrow) * PS + ks2 * 32 + lk];
#pragma unroll
            for (int dt = 0; dt < 8; dt++) {
                short8 vbf = *(const short8*)&Vt[(dt * 16 + lrow) * VS + ks2 * 32 + lk];
                oacc[dt] = MFMA16(pa, vbf, oacc[dt]);
            }
        }
    }

#pragma unroll
    for (int r = 0; r < 4; r++) {
        const int rowi = b * 2048 + qt * 64 + w * 16 + g * 4 + r;
        if (SPLIT) {
            const size_t obase = ((size_t)s * 16384 + rowi) * 128;
#pragma unroll
            for (int dt = 0; dt < 8; dt++)
                Oout[obase + dt * 16 + lrow] = oacc[dt][r];
            if (lrow == 0) {
                const size_t mb = ((size_t)s * 16384 + rowi) * 2;
                Ml[mb] = m_r[r];
                Ml[mb + 1] = l_r[r];
            }
        } else {
            const float inv = 1.0f / l_r[r];
#pragma unroll
            for (int dt = 0; dt < 8; dt++)
                Oout[(size_t)rowi * 128 + dt * 16 + lrow] = oacc[dt][r] * inv;
        }
    }
}

// ---------------------------------------------------------------------------
// Kernel 2b: merge 3 split partials.
// ---------------------------------------------------------------------------
__global__ __launch_bounds__(256) void attn_merge(const float* __restrict__ Oacc,
                                                  const float* __restrict__ Ml,
                                                  float* __restrict__ out) {
    const int row = blockIdx.x * 2 + (threadIdx.x >> 7);
    const int c = threadIdx.x & 127;
    const float m0 = Ml[(size_t)(0 * 16384 + row) * 2], l0 = Ml[(size_t)(0 * 16384 + row) * 2 + 1];
    const float m1 = Ml[(size_t)(1 * 16384 + row) * 2], l1 = Ml[(size_t)(1 * 16384 + row) * 2 + 1];
    const float m2 = Ml[(size_t)(2 * 16384 + row) * 2], l2 = Ml[(size_t)(2 * 16384 + row) * 2 + 1];
    const float M = fmaxf(m0, fmaxf(m1, m2));
    const float w0 = __expf(m0 - M), w1 = __expf(m1 - M), w2 = __expf(m2 - M);
    const float D = w0 * l0 + w1 * l1 + w2 * l2;
    const float o = w0 * Oacc[(size_t)(0 * 16384 + row) * 128 + c] +
                    w1 * Oacc[(size_t)(1 * 16384 + row) * 128 + c] +
                    w2 * Oacc[(size_t)(2 * 16384 + row) * 128 + c];
    out[(size_t)row * 128 + c] = o / D;
}

// ---------------------------------------------------------------------------
extern "C" void kernel_launch(void* const* d_in, const int* in_sizes, int n_in,
                              void* d_out, int out_size, void* d_ws, size_t ws_size,
                              hipStream_t stream) {
    const float* x  = (const float*)d_in[0];
    const float* Wq = (const float*)d_in[1];
    const float* Wk = (const float*)d_in[2];
    const float* Wv = (const float*)d_in[3];
    float* out = (float*)d_out;

    unsigned short* ws = (unsigned short*)d_ws;
    unsigned short* qb = ws;                                   // 16384*128 bf16
    unsigned short* kb = qb + (size_t)16384 * 128;
    unsigned short* vb = kb + (size_t)16384 * 128;
    unsigned short* Wt = vb + (size_t)16384 * 128;             // 3*128*2048 bf16
    float* Oacc = (float*)(Wt + (size_t)3 * 128 * 2048);       // 3*16384*128 f32
    float* Ml = Oacc + (size_t)3 * 16384 * 128;                // 3*16384*2 f32
    const size_t ws_need = (size_t)((char*)(Ml + (size_t)3 * 16384 * 2) - (char*)d_ws);

    hipLaunchKernelGGL(wt_kernel, dim3(32, 2, 3), dim3(256), 0, stream, Wq, Wk, Wv, Wt);
    hipLaunchKernelGGL(qkv_gemm, dim3(768), dim3(256), 0, stream, x, Wt, qb);
    if (ws_size >= ws_need) {
        hipLaunchKernelGGL((attn_kernel_t<true>), dim3(32, 8, 3), dim3(256), 0, stream,
                           qb, kb, vb, Oacc, Ml);
        hipLaunchKernelGGL(attn_merge, dim3(8192), dim3(256), 0, stream, Oacc, Ml, out);
    } else {
        hipLaunchKernelGGL((attn_kernel_t<false>), dim3(32, 8), dim3(256), 0, stream,
                           qb, kb, vb, out, (float*)nullptr);
    }
}